// Round 1
// baseline (1762.771 us; speedup 1.0000x reference)
//
#include <hip/hip_runtime.h>
#include <hip/hip_bf16.h>
#include <math.h>

// TemporalAttention: T=512, N=1024, D=256
//   e = score_w . tanh(H @ fc_w^T + fc_b)       (bf16 MFMA GEMM, B staged in LDS)
//   coefficients A_t,B_t via wave-parallel online-softmax prefix scan (fused)
//   C[t] = A_t*C[t-1] + B_t*H[t]                (streaming FMA scan, depth-4 prefetch)

#define T_DIM 512
#define N_DIM 1024
#define D_DIM 256

typedef short v8s __attribute__((ext_vector_type(8)));   // 8 bf16 (4 VGPRs)
typedef float v4f __attribute__((ext_vector_type(4)));   // 4 fp32 acc

__device__ __forceinline__ unsigned pk_bf16(float a, float b) {
    // RNE fp32->bf16, packed pair (b in high 16)
    unsigned ua = __builtin_bit_cast(unsigned, a);
    unsigned ub = __builtin_bit_cast(unsigned, b);
    ua = ua + 0x7fffu + ((ua >> 16) & 1u);
    ub = ub + 0x7fffu + ((ub >> 16) & 1u);
    return (ua >> 16) | (ub & 0xffff0000u);
}

__device__ __forceinline__ float fast_tanh(float x) {
    // tanh(x) = 1 - 2/(exp(2x)+1); handles +-inf limits correctly
    float e = __expf(2.0f * x);
    return 1.0f - 2.0f / (e + 1.0f);
}

// ---------------------------------------------------------------------------
// Kernel 1: e[t*N+n] = score_w . tanh(H_row @ fc_w^T + fc_b)
// B (fc_w, bf16) lives in LDS (128 KB), chunk layout [ks*4+quad][j] so a
// wave's ds_read_b128 of a (jt,ks) fragment is bank-conflict-free.
// Each wave is fully independent: owns whole 16-row tiles, all 256 j-cols.
// No barriers in the main loop, no cross-wave reduction, no redundant A loads.
// ---------------------------------------------------------------------------
#define SCORE_BLOCKS 256
#define SCORE_WAVES  (SCORE_BLOCKS * 8)

__global__ __launch_bounds__(512, 2) void k_score(
    const float* __restrict__ H, const float* __restrict__ fc_w,
    const float* __restrict__ fc_b, const float* __restrict__ score_w,
    float* __restrict__ e_out)
{
    __shared__ uint4 Bs[8192];   // 128 KB: chunk c = (ks*4+quad)*256 + j

    const int tid  = threadIdx.x;          // 0..511
    const int l    = tid & 63;
    const int l15  = l & 15;
    const int quad = l >> 4;

    // --- stage fc_w -> LDS as bf16 (coalesced global reads: 32B/thread) ---
#pragma unroll
    for (int r = 0; r < 16; ++r) {
        int c  = r * 512 + tid;            // 0..8191
        int j  = c >> 5;                   // 0..255
        int q4 = c & 31;                   // ks*4+quad
        const float4* p = (const float4*)(fc_w + j * D_DIM + q4 * 8);
        float4 b0 = p[0], b1 = p[1];
        uint4 u;
        u.x = pk_bf16(b0.x, b0.y); u.y = pk_bf16(b0.z, b0.w);
        u.z = pk_bf16(b1.x, b1.y); u.w = pk_bf16(b1.z, b1.w);
        Bs[q4 * 256 + j] = u;
    }

    // per-lane bias / score weights for its 16 j's (j = jt*16 + l15)
    float fcb[16], scw[16];
#pragma unroll
    for (int jt = 0; jt < 16; ++jt) {
        fcb[jt] = fc_b[jt * 16 + l15];
        scw[jt] = score_w[jt * 16 + l15];
    }

    __syncthreads();   // Bs ready; read-only afterwards -> no more barriers

    const v8s* Bv = (const v8s*)Bs;
    const int cbase = quad * 256 + l15;    // per-lane chunk offset

    const int gw = blockIdx.x * 8 + (tid >> 6);    // global wave id 0..2047
    const int n_tiles = (T_DIM * N_DIM) / 16;      // 32768

    for (int mt = gw; mt < n_tiles; mt += SCORE_WAVES) {
        const float* hrow = H + (size_t)(mt * 16 + l15) * D_DIM + quad * 8;

        // A-tile: 16 rows x 256 k, this wave only (no redundancy)
        v8s af[8];
#pragma unroll
        for (int ks = 0; ks < 8; ++ks) {
            const float4* p = (const float4*)(hrow + ks * 32);
            float4 a0 = p[0], a1 = p[1];
            union { v8s v; unsigned u[4]; } f;
            f.u[0] = pk_bf16(a0.x, a0.y); f.u[1] = pk_bf16(a0.z, a0.w);
            f.u[2] = pk_bf16(a1.x, a1.y); f.u[3] = pk_bf16(a1.z, a1.w);
            af[ks] = f.v;
        }

        v4f acc[16];
        const v4f vz = {0.f, 0.f, 0.f, 0.f};
#pragma unroll
        for (int jt = 0; jt < 16; ++jt) acc[jt] = vz;

        // ks outer / jt inner: 16 independent MFMAs between dependences
#pragma unroll
        for (int ks = 0; ks < 8; ++ks) {
#pragma unroll
            for (int jt = 0; jt < 16; ++jt) {
                v8s bf = Bv[ks * 1024 + jt * 16 + cbase];
                acc[jt] = __builtin_amdgcn_mfma_f32_16x16x32_bf16(
                    af[ks], bf, acc[jt], 0, 0, 0);
            }
        }

        // epilogue: tanh, score-weight, reduce over the 16 l15 lanes
        // C/D layout: col(j)=l15, row = quad*4 + r
        float er[4];
#pragma unroll
        for (int r = 0; r < 4; ++r) {
            float s = 0.f;
#pragma unroll
            for (int jt = 0; jt < 16; ++jt)
                s += fast_tanh(acc[jt][r] + fcb[jt]) * scw[jt];
            er[r] = s;
        }
#pragma unroll
        for (int msk = 1; msk < 16; msk <<= 1) {
#pragma unroll
            for (int r = 0; r < 4; ++r)
                er[r] += __shfl_xor(er[r], msk, 64);
        }
        if (l15 == 0) {
#pragma unroll
            for (int r = 0; r < 4; ++r)
                e_out[mt * 16 + quad * 4 + r] = er[r];
        }
    }
}

// ---------------------------------------------------------------------------
// Kernel 2: per-n column: (a) wave 0 computes coefficients A_t,B_t via a
// wave-parallel online-softmax prefix scan into LDS; (b) all 4 waves stream
// C[t,n,:] = A_t*C[t-1,n,:] + B_t*H[t,n,:] with depth-4 prefetch.
// ---------------------------------------------------------------------------
__global__ __launch_bounds__(256) void k_apply(
    const float* __restrict__ H, const float* __restrict__ e,
    float* __restrict__ C)
{
    __shared__ float2 coef[T_DIM];   // 4 KB

    const int n   = blockIdx.x;
    const int tid = threadIdx.x;

    if (tid < 64) {
        // lane handles t = tid*8 .. tid*8+7
        float ev[8];
#pragma unroll
        for (int i = 0; i < 8; ++i)
            ev[i] = e[(tid * 8 + i) * N_DIM + n];

        // lane-local inclusive (m,s) fold
        float m = -INFINITY, s = 0.f;
#pragma unroll
        for (int i = 0; i < 8; ++i) {
            float mn = fmaxf(m, ev[i]);
            s = s * __expf(m - mn) + __expf(ev[i] - mn);
            m = mn;
        }
        // wave inclusive scan (associative combine of (m,s))
#pragma unroll
        for (int off = 1; off < 64; off <<= 1) {
            float mo = __shfl_up(m, off, 64);
            float so = __shfl_up(s, off, 64);
            if (tid >= off) {
                float mn = fmaxf(mo, m);
                s = s * __expf(m - mn) + so * __expf(mo - mn);
                m = mn;
            }
        }
        // exclusive prefix for this lane
        float pm = __shfl_up(m, 1, 64);
        float ps = __shfl_up(s, 1, 64);
        if (tid == 0) { pm = -INFINITY; ps = 0.f; }

        // replay the 8 steps from the carry-in, emitting A_t, B_t
        float mm = pm, ss = ps;
#pragma unroll
        for (int i = 0; i < 8; ++i) {
            float et    = ev[i];
            float mn    = fmaxf(mm, et);
            float alpha = __expf(mm - mn);
            float p     = __expf(et - mn);
            float sn    = ss * alpha + p;
            float rs    = 1.0f / sn;
            coef[tid * 8 + i] = make_float2(alpha * ss * rs, p * rs);
            mm = mn; ss = sn;
        }
    }
    __syncthreads();

    // phase 2: stream. 256 threads = one fp32 lane per d.
    const size_t base = (size_t)n * D_DIM + tid;
    const float* Hp = H + base;
    float*       Cp = C + base;
    const size_t st = (size_t)N_DIM * D_DIM;

    float num = 0.f;
    float  h0 = Hp[0],        h1 = Hp[st];
    float  h2 = Hp[2 * st],   h3 = Hp[3 * st];
    float2 a0 = coef[0], a1 = coef[1], a2 = coef[2], a3 = coef[3];

    for (int t = 0; t < T_DIM; ++t) {
        float  h4 = 0.f;
        float2 a4 = make_float2(0.f, 0.f);
        if (t + 4 < T_DIM) {
            h4 = Hp[(size_t)(t + 4) * st];
            a4 = coef[t + 4];
        }
        num = fmaf(num, a0.x, a0.y * h0);
        Cp[(size_t)t * st] = num;
        h0 = h1; h1 = h2; h2 = h3; h3 = h4;
        a0 = a1; a1 = a2; a2 = a3; a3 = a4;
    }
}

// ---------------------------------------------------------------------------
extern "C" void kernel_launch(void* const* d_in, const int* in_sizes, int n_in,
                              void* d_out, int out_size, void* d_ws, size_t ws_size,
                              hipStream_t stream) {
    const float* H       = (const float*)d_in[0];
    const float* fc_w    = (const float*)d_in[1];
    const float* fc_b    = (const float*)d_in[2];
    const float* score_w = (const float*)d_in[3];
    float* C = (float*)d_out;

    float* e = (float*)d_ws;   // 2 MB

    k_score<<<dim3(SCORE_BLOCKS), dim3(512), 0, stream>>>(H, fc_w, fc_b, score_w, e);
    k_apply<<<dim3(N_DIM), dim3(256), 0, stream>>>(H, e, C);
}